// Round 1
// baseline (134.264 us; speedup 1.0000x reference)
//
#include <hip/hip_runtime.h>

// RFCM loss, fused single pass + finalize. B=2, K=4, D=H=W=128. Scalar out.
//
// mean(J1) = (1/(B*N)) * sum_{b,k} [ A_bk - Sim_bk^2 / Sm_bk ]
//   Sm=sum mem, Sim=sum mem*img, A=sum mem*img^2, mem=y_pred^2
// mean(J2) = (1/(B*N)) * sum_n [ Sm*Sbk - Sm^2 - sum_k m*bk + sum_k m^2 ]
//   bk = box27(mem_k) incl center, zero pad.
//
// R11: registers-only staging. R10 (barrier-free LDS DMA) was latency-bound:
// VALUBusy 19.7%, occupancy 15.7% (64KB LDS -> 2 blocks/CU), vmcnt(0) full
// drains with 1-plane prefetch. Here each lane loads 2 raw rows per plane
// (own row + one halo row; half-waves split the halo), and the missing
// middle term of the vertical 3-sum comes from the partner half-wave via
// __shfl_xor(.,32): identical traffic to R10's staging, zero LDS, and the
// compiler can emit fine-grained per-consumer vmcnt(N) instead of drains.
// SD=8 -> 4: grid 512 -> 1024 blocks, 4096 waves (16/CU max) for latency
// hiding, at +20% d-halo traffic (planes 6/4 instead of 10/8).
// NEVER __launch_bounds__ min-waves (R4/R6: VGPR=64 -> 240-330MB spills).

#define BB 2
#define KK 4
#define DD 128
#define HH 128
#define WW 128
#define PLANE (HH * WW)
#define SD 4
#define NBD (DD / SD)   // 32
#define HR 8            // rows per block (4 waves x 2 rows)
#define NBH (HH / HR)   // 16
#define NT 256

__global__ __launch_bounds__(NT) void rfcm_main(
    const float* __restrict__ yp, const float* __restrict__ img,
    double* __restrict__ ws)
{
    __shared__ double red[4 * 13];   // 416 B: reduction scratch only

    const int tid = threadIdx.x;
    const int wv  = tid >> 6;       // wave 0..3
    const int L   = tid & 63;
    const int wl  = L & 31;         // w-lane: owns cols c0..c0+3
    const int hy  = L >> 5;         // 0..1: own row within wave pair
    const int c0  = wl << 2;

    // XCD swizzle: slab (b,dsb) -> XCD slab%8; its 16 h-tiles share one L2.
    const int bid  = blockIdx.x;
    const int xcd  = bid & 7;
    const int idx  = bid >> 3;       // 0..127
    const int sl   = idx >> 4;       // 0..7
    const int ht   = idx & 15;
    const int slab = sl * 8 + xcd;   // 0..63
    const int b    = slab >> 5;
    const int dsb  = slab & 31;

    const int h0  = ht * HR;
    const int hp0 = h0 + (wv << 1);  // wave's first owned row
    const int h   = hp0 + hy;        // own row
    const int d0  = dsb * SD;

    // halo row this lane loads (hy=0 -> hp0-1, hy=1 -> hp0+2), clamped+scaled
    const int gHr = (hy == 0) ? (hp0 - 1) : (hp0 + 2);
    const int gH  = gHr < 0 ? 0 : (gHr > HH - 1 ? HH - 1 : gHr);
    const float hsc = (gHr >= 0 && gHr <= HH - 1) ? 1.f : 0.f;

    const bool okL = (wl > 0), okR = (wl < 31);

    const float* pO[KK];
    const long dH = (long)(gH - h) * WW;   // own-row -> halo-row offset (floats)
    #pragma unroll
    for (int k = 0; k < KK; k++)
        pO[k] = yp + (size_t)((b * KK + k) * DD) * PLANE + (size_t)h * WW + c0;

    // raw double-buffers (named; all indexing static under full unroll)
    float4 oA[KK], aA[KK], oB[KK], aB[KK];

    auto lplane = [&](int t, float4* o, float4* a) {
        const size_t off = (size_t)t * PLANE;
        #pragma unroll
        for (int k = 0; k < KK; k++) {
            o[k] = *(const float4*)(pO[k] + off);
            a[k] = *(const float4*)(pO[k] + off + dH);
        }
    };

    // raw(own,halo) -> hw9 sums + center squares for one cluster, one plane.
    // Vertical 3-sum: own^2 + partner-half-wave own^2 (shfl_xor 32) + halo^2*hsc.
    auto extract = [&](const float4 o4, const float4 a4, float4& s9, float4& mm) {
        const float4 m = make_float4(o4.x*o4.x, o4.y*o4.y, o4.z*o4.z, o4.w*o4.w);
        mm = m;
        float4 p;
        p.x = __shfl_xor(m.x, 32, 64);
        p.y = __shfl_xor(m.y, 32, 64);
        p.z = __shfl_xor(m.z, 32, 64);
        p.w = __shfl_xor(m.w, 32, 64);
        float4 v;
        v.x = fmaf(a4.x*a4.x, hsc, m.x + p.x);
        v.y = fmaf(a4.y*a4.y, hsc, m.y + p.y);
        v.z = fmaf(a4.z*a4.z, hsc, m.z + p.z);
        v.w = fmaf(a4.w*a4.w, hsc, m.w + p.w);
        const float vL = okL ? __shfl_up(v.w, 1)   : 0.f;
        const float vR = okR ? __shfl_down(v.x, 1) : 0.f;
        s9.x = vL  + v.x + v.y;
        s9.y = v.x + v.y + v.z;
        s9.z = v.y + v.z + v.w;
        s9.w = v.z + v.w + vR;
    };

    const float* imgb = img + (size_t)b * DD * PLANE + (size_t)h * WW + c0;

    // ---- prolog ----
    const bool vprev = (d0 > 0);
    lplane(vprev ? d0 - 1 : 0, oA, aA);      // plane d0-1 (dummy plane 0 if edge)
    lplane(d0, oB, aB);
    float4 iv = *(const float4*)(imgb + (size_t)d0 * PLANE);

    float4 s9p[KK], s9c[KK], mc[KK], dum;
    #pragma unroll
    for (int k = 0; k < KK; k++) extract(oA[k], aA[k], s9p[k], dum);
    if (!vprev) {
        #pragma unroll
        for (int k = 0; k < KK; k++) s9p[k] = make_float4(0.f, 0.f, 0.f, 0.f);
    }
    lplane(d0 + 1, oA, aA);                  // d0+1 <= 125: always valid
    #pragma unroll
    for (int k = 0; k < KK; k++) extract(oB[k], aB[k], s9c[k], mc[k]);

    float smf[KK] = {0,0,0,0}, sif[KK] = {0,0,0,0}, saf[KK] = {0,0,0,0};
    float j2f = 0.f;

    // step i (plane d): consume raw(d+1) from C-buf, prefetch raw(d+2) into P-buf.
    auto step = [&](int i, float4* oC, float4* aC, float4* oP, float4* aP) {
        const int d = d0 + i;
        const bool vn = (d + 1 < DD);        // wave-uniform
        float4 ivn = iv;
        if (vn) ivn = *(const float4*)(imgb + (size_t)(d + 1) * PLANE);
        if (i < SD - 1 && d + 2 < DD) lplane(d + 2, oP, aP);

        const float4 iv2 = make_float4(iv.x*iv.x, iv.y*iv.y, iv.z*iv.z, iv.w*iv.w);
        float4 summ  = make_float4(0.f, 0.f, 0.f, 0.f);
        float4 sumbk = make_float4(0.f, 0.f, 0.f, 0.f);
        float4 cross = make_float4(0.f, 0.f, 0.f, 0.f);

        #pragma unroll
        for (int k = 0; k < KK; k++) {
            float4 s9n, mn;
            if (vn) extract(oC[k], aC[k], s9n, mn);
            else { s9n = make_float4(0.f,0.f,0.f,0.f); mn = s9n; }

            const float4 m = mc[k];
            float4 bk;
            bk.x = s9p[k].x + s9c[k].x + s9n.x;
            bk.y = s9p[k].y + s9c[k].y + s9n.y;
            bk.z = s9p[k].z + s9c[k].z + s9n.z;
            bk.w = s9p[k].w + s9c[k].w + s9n.w;

            summ.x += m.x; summ.y += m.y; summ.z += m.z; summ.w += m.w;
            sumbk.x += bk.x; sumbk.y += bk.y; sumbk.z += bk.z; sumbk.w += bk.w;
            cross.x = fmaf(m.x, bk.x - m.x, cross.x);
            cross.y = fmaf(m.y, bk.y - m.y, cross.y);
            cross.z = fmaf(m.z, bk.z - m.z, cross.z);
            cross.w = fmaf(m.w, bk.w - m.w, cross.w);

            smf[k] += (m.x + m.y) + (m.z + m.w);
            sif[k] = fmaf(m.x, iv.x,  fmaf(m.y, iv.y,  fmaf(m.z, iv.z,  fmaf(m.w, iv.w,  sif[k]))));
            saf[k] = fmaf(m.x, iv2.x, fmaf(m.y, iv2.y, fmaf(m.z, iv2.z, fmaf(m.w, iv2.w, saf[k]))));

            s9p[k] = s9c[k]; s9c[k] = s9n; mc[k] = mn;
        }

        j2f += (summ.x * (sumbk.x - summ.x) - cross.x)
             + (summ.y * (sumbk.y - summ.y) - cross.y)
             + (summ.z * (sumbk.z - summ.z) - cross.z)
             + (summ.w * (sumbk.w - summ.w) - cross.w);

        iv = ivn;
    };

    #pragma unroll
    for (int ii = 0; ii < SD / 2; ii++) {
        step(2 * ii,     oA, aA, oB, aB);
        step(2 * ii + 1, oB, aB, oA, aA);
    }

    // ---- block reduction of 13 scalars ----
    double q[13];
    #pragma unroll
    for (int k = 0; k < KK; k++) {
        q[k] = (double)smf[k]; q[4 + k] = (double)sif[k]; q[8 + k] = (double)saf[k];
    }
    q[12] = (double)j2f;

    #pragma unroll
    for (int qq = 0; qq < 13; qq++) {
        double v = q[qq];
        #pragma unroll
        for (int off = 32; off > 0; off >>= 1) v += __shfl_down(v, off, 64);
        q[qq] = v;
    }

    const int lane = tid & 63, wid = tid >> 6;
    if (lane == 0) {
        #pragma unroll
        for (int qq = 0; qq < 13; qq++) red[wid * 13 + qq] = q[qq];
    }
    __syncthreads();
    if (tid < 13) {
        const double sfin = red[tid] + red[13 + tid] + red[26 + tid] + red[39 + tid];
        int idxo;
        if      (tid < 4)  idxo = b * KK + tid;              // Sm
        else if (tid < 8)  idxo = 8  + b * KK + (tid - 4);   // Sim
        else if (tid < 12) idxo = 16 + b * KK + (tid - 8);   // A
        else               idxo = 24;                        // J2
        unsafeAtomicAdd(&ws[idxo], sfin);
    }
}

__global__ void rfcm_fin(const double* __restrict__ ws, float* __restrict__ out)
{
    if (threadIdx.x == 0 && blockIdx.x == 0) {
        double j1 = 0;
        #pragma unroll
        for (int i = 0; i < BB * KK; i++)
            j1 += ws[16 + i] - ws[8 + i] * ws[8 + i] / ws[i];
        const double invBN = 1.0 / ((double)BB * (double)DD * (double)HH * (double)WW);
        out[0] = (float)(j1 * invBN + 0.0008 * ws[24] * invBN);
    }
}

extern "C" void kernel_launch(void* const* d_in, const int* in_sizes, int n_in,
                              void* d_out, int out_size, void* d_ws, size_t ws_size,
                              hipStream_t stream) {
    const float* yp  = (const float*)d_in[0];   // y_pred [2,4,128,128,128]
    const float* img = (const float*)d_in[1];   // image  [2,1,128,128,128]
    float* out = (float*)d_out;
    double* ws = (double*)d_ws;

    hipMemsetAsync(d_ws, 0, 25 * sizeof(double), stream);

    dim3 grid(BB * NBD * NBH);   // 1024 blocks, no LDS cap on occupancy
    rfcm_main<<<grid, NT, 0, stream>>>(yp, img, ws);
    rfcm_fin<<<1, 64, 0, stream>>>(ws, out);
}

// Round 3
// 132.508 us; speedup vs baseline: 1.0133x; 1.0133x over previous
//
#include <hip/hip_runtime.h>

// RFCM loss, fused single pass + finalize. B=2, K=4, D=H=W=128. Scalar out.
//
// mean(J1) = (1/(B*N)) * sum_{b,k} [ A_bk - Sim_bk^2 / Sm_bk ]
//   Sm=sum mem, Sim=sum mem*img, A=sum mem*img^2, mem=y_pred^2
// mean(J2) = (1/(B*N)) * sum_n [ Sm*Sbk - Sm^2 - sum_k m*bk + sum_k m^2 ]
//   bk = box27(mem_k) incl center, zero pad. s9 = 3x3 in-plane box sum.
//   Decompose over planes: bk_d = s9_{d-1}+s9_d+s9_{d+1}; accumulate the
//   3 diagonal bands (d=t, d=t-1, d=t+1) at extract time of plane t with
//   one plane of history (m_prev,s9_prev,M_prev,S_prev). Slab-edge gating:
//   P-band skipped at i=0 (owned by prev slab's epilog); epilog adds only
//   the P-band for plane d0+SD.
//
// R13 == R12 resubmitted: round-2 bench died with "MI355X container failed
// twice" (broker/infra, no kernel result). Source audited: no OOB (all
// plane indices in [0,127], gated reloads), no hang paths, band algebra
// re-verified. Theory still untested, so rerun unchanged.
//
// R12: occupancy via VGPR<=128. R10/R11 post-mortem: every variant ended
// at <=8 waves/CU (R10: 64KB LDS -> 2 blocks/CU; R11: VGPR=148 > 128 ->
// 2 waves/SIMD) and all pinned at ~1.2 TB/s fetch = latency-bound convoy,
// VALUBusy ~18%. Lever: 4 waves/SIMD needs VGPR<=128. Restructure:
//  - 1 row/wave, float2 lanes (64x2 = 128 cols); each lane loads its 3
//    vertical rows (L1 dedups wave overlap) -> no shfl_xor, staging 6
//    regs/cluster/plane, double-buffered = 48 regs.
//  - extract-time accumulation kills the s9p/s9c/s9n/mc ring (-28 regs).
//  - SD=8 (d-halo 1.25x), grid 2*16*32=1024 blocks = 4 blocks/CU = 16
//    waves/CU, exactly the 4-waves/SIMD cap.
// NEVER __launch_bounds__ min-waves (R4/R6: VGPR=64 -> 240-330MB spills).

#define BB 2
#define KK 4
#define DD 128
#define HH 128
#define WW 128
#define PLANE (HH * WW)
#define SD 8
#define NBD (DD / SD)   // 16
#define HRB 4           // rows per block = 4 waves x 1 row
#define NBH (HH / HRB)  // 32
#define NT 256

__global__ __launch_bounds__(NT) void rfcm_main(
    const float* __restrict__ yp, const float* __restrict__ img,
    double* __restrict__ ws)
{
    __shared__ double red[4 * 13];   // 416 B reduction scratch

    const int tid = threadIdx.x;
    const int wv  = tid >> 6;        // wave 0..3 -> row within block
    const int L   = tid & 63;
    const int c0  = L << 1;          // 2 cols per lane

    // XCD swizzle: slab (b,dsb) -> XCD slab%8; its 32 h-tiles share one L2.
    const int bid  = blockIdx.x;
    const int xcd  = bid & 7;
    const int idx  = bid >> 3;       // 0..127
    const int sl   = idx >> 5;       // 0..3
    const int ht   = idx & 31;       // 0..31
    const int slab = sl * 8 + xcd;   // 0..31
    const int b    = slab >> 4;
    const int dsb  = slab & 15;

    const int h  = ht * HRB + wv;    // own row (wave-uniform)
    const int d0 = dsb * SD;

    const float su = (h > 0)      ? 1.f : 0.f;   // wave-uniform edge scales
    const float sd = (h < HH - 1) ? 1.f : 0.f;
    const int   oU = (h > 0)      ? -WW : 0;     // clamped row offsets
    const int   oD = (h < HH - 1) ?  WW : 0;

    const bool okL = (L > 0), okR = (L < 63);

    const float* pk[KK];
    #pragma unroll
    for (int k = 0; k < KK; k++)
        pk[k] = yp + (size_t)((b * KK + k) * DD) * PLANE + (size_t)h * WW + c0;
    const float* imgb = img + (size_t)b * DD * PLANE + (size_t)h * WW + c0;

    // staging: 3 rows (up/own/dn) x 4 clusters, double-buffered
    float2 uA[KK], oA[KK], dA[KK], uB[KK], oB[KK], dB[KK];

    auto lplane = [&](int t, float2* u, float2* o, float2* d) {
        const size_t off = (size_t)t * PLANE;
        #pragma unroll
        for (int k = 0; k < KK; k++) {
            const float* p = pk[k] + off;
            u[k] = *(const float2*)(p + oU);
            o[k] = *(const float2*)(p);
            d[k] = *(const float2*)(p + oD);
        }
    };

    // rows -> center squares m + 3x3 box sum s9 (both f2, per cluster)
    auto extract = [&](const float2 u, const float2 o, const float2 dn,
                       float2& m, float2& s9) {
        m.x = o.x * o.x; m.y = o.y * o.y;
        float2 v;
        v.x = fmaf(u.x * u.x, su, fmaf(dn.x * dn.x, sd, m.x));
        v.y = fmaf(u.y * u.y, su, fmaf(dn.y * dn.y, sd, m.y));
        const float vl = okL ? __shfl_up(v.y, 1)   : 0.f;
        const float vr = okR ? __shfl_down(v.x, 1) : 0.f;
        s9.x = vl + v.x + v.y;
        s9.y = v.x + v.y + vr;
    };

    // ---- prolog: planes d0-1 (history) and d0 in flight ----
    const int tp = (d0 > 0) ? d0 - 1 : d0;
    lplane(tp, uA, oA, dA);
    lplane(d0, uB, oB, dB);
    float2 iv = *(const float2*)(imgb + (size_t)d0 * PLANE);

    float2 mp[KK], sp[KK];
    float2 Mp, Sp; Mp.x = Mp.y = Sp.x = Sp.y = 0.f;
    #pragma unroll
    for (int k = 0; k < KK; k++) {
        float2 m, s9;
        extract(uA[k], oA[k], dA[k], m, s9);
        mp[k] = m; sp[k] = s9;
        Mp.x += m.x; Mp.y += m.y; Sp.x += s9.x; Sp.y += s9.y;
    }
    if (d0 == 0) {   // no previous plane: zero history
        #pragma unroll
        for (int k = 0; k < KK; k++) {
            mp[k].x = mp[k].y = 0.f; sp[k].x = sp[k].y = 0.f;
        }
        Mp.x = Mp.y = Sp.x = Sp.y = 0.f;
    }
    lplane(d0 + 1, uA, oA, dA);      // prefetch (d0+1 <= 121, always valid)

    float smf[KK] = {0,0,0,0}, sif[KK] = {0,0,0,0}, saf[KK] = {0,0,0,0};
    float j2f = 0.f;

    // step i: consume plane t=d0+i from C-buf; reload C-buf with t+2.
    auto step = [&](int i, float2* uC, float2* oC, float2* dC) {
        const int t = d0 + i;
        float2 ivn = iv;
        if (i < SD - 1) ivn = *(const float2*)(imgb + (size_t)(t + 1) * PLANE);
        const bool reload = (i < SD - 2) || (i == SD - 2 && d0 + SD < DD);
        const size_t off2 = (size_t)(t + 2) * PLANE;

        const float ivx2 = iv.x * iv.x, ivy2 = iv.y * iv.y;
        float2 M, S; M.x = M.y = S.x = S.y = 0.f;
        float q = 0.f, ctt = 0.f, ctp = 0.f, cpt = 0.f;

        #pragma unroll
        for (int k = 0; k < KK; k++) {
            float2 m, s9;
            extract(uC[k], oC[k], dC[k], m, s9);
            if (reload) {                     // reload freed regs with t+2
                const float* p = pk[k] + off2;
                uC[k] = *(const float2*)(p + oU);
                oC[k] = *(const float2*)(p);
                dC[k] = *(const float2*)(p + oD);
            }
            M.x += m.x; M.y += m.y; S.x += s9.x; S.y += s9.y;
            q   = fmaf(m.x, m.x,      fmaf(m.y, m.y,      q));
            ctt = fmaf(m.x, s9.x,     fmaf(m.y, s9.y,     ctt));
            ctp = fmaf(m.x, sp[k].x,  fmaf(m.y, sp[k].y,  ctp));
            if (i > 0)
                cpt = fmaf(mp[k].x, s9.x, fmaf(mp[k].y, s9.y, cpt));
            smf[k] += m.x + m.y;
            sif[k] = fmaf(m.x, iv.x, fmaf(m.y, iv.y, sif[k]));
            saf[k] = fmaf(m.x, ivx2, fmaf(m.y, ivy2, saf[k]));
            mp[k] = m; sp[k] = s9;
        }

        // diagonal band (d=t) + T-prev band (d=t, s9_{t-1}) + P band (d=t-1)
        j2f += (M.x * S.x + M.y * S.y) - (M.x * M.x + M.y * M.y) + q - ctt
             + (M.x * Sp.x + M.y * Sp.y) - ctp;
        if (i > 0)
            j2f += (Mp.x * S.x + Mp.y * S.y) - cpt;

        Mp = M; Sp = S;
        iv = ivn;
    };

    #pragma unroll
    for (int ii = 0; ii < SD / 2; ii++) {
        step(2 * ii,     uB, oB, dB);
        step(2 * ii + 1, uA, oA, dA);
    }

    // epilog: P band for plane d0+SD (skipped at volume edge)
    if (d0 + SD < DD) {
        float2 S; S.x = S.y = 0.f;
        float cpt = 0.f;
        #pragma unroll
        for (int k = 0; k < KK; k++) {
            float2 m, s9;
            extract(uB[k], oB[k], dB[k], m, s9);
            S.x += s9.x; S.y += s9.y;
            cpt = fmaf(mp[k].x, s9.x, fmaf(mp[k].y, s9.y, cpt));
        }
        j2f += (Mp.x * S.x + Mp.y * S.y) - cpt;
    }

    // ---- block reduction of 13 scalars ----
    double qd[13];
    #pragma unroll
    for (int k = 0; k < KK; k++) {
        qd[k] = (double)smf[k]; qd[4 + k] = (double)sif[k]; qd[8 + k] = (double)saf[k];
    }
    qd[12] = (double)j2f;

    #pragma unroll
    for (int qq = 0; qq < 13; qq++) {
        double v = qd[qq];
        #pragma unroll
        for (int off = 32; off > 0; off >>= 1) v += __shfl_down(v, off, 64);
        qd[qq] = v;
    }

    const int lane = tid & 63, wid = tid >> 6;
    if (lane == 0) {
        #pragma unroll
        for (int qq = 0; qq < 13; qq++) red[wid * 13 + qq] = qd[qq];
    }
    __syncthreads();
    if (tid < 13) {
        const double sfin = red[tid] + red[13 + tid] + red[26 + tid] + red[39 + tid];
        int idxo;
        if      (tid < 4)  idxo = b * KK + tid;              // Sm
        else if (tid < 8)  idxo = 8  + b * KK + (tid - 4);   // Sim
        else if (tid < 12) idxo = 16 + b * KK + (tid - 8);   // A
        else               idxo = 24;                        // J2
        unsafeAtomicAdd(&ws[idxo], sfin);
    }
}

__global__ void rfcm_fin(const double* __restrict__ ws, float* __restrict__ out)
{
    if (threadIdx.x == 0 && blockIdx.x == 0) {
        double j1 = 0;
        #pragma unroll
        for (int i = 0; i < BB * KK; i++)
            j1 += ws[16 + i] - ws[8 + i] * ws[8 + i] / ws[i];
        const double invBN = 1.0 / ((double)BB * (double)DD * (double)HH * (double)WW);
        out[0] = (float)(j1 * invBN + 0.0008 * ws[24] * invBN);
    }
}

extern "C" void kernel_launch(void* const* d_in, const int* in_sizes, int n_in,
                              void* d_out, int out_size, void* d_ws, size_t ws_size,
                              hipStream_t stream) {
    const float* yp  = (const float*)d_in[0];   // y_pred [2,4,128,128,128]
    const float* img = (const float*)d_in[1];   // image  [2,1,128,128,128]
    float* out = (float*)d_out;
    double* ws = (double*)d_ws;

    hipMemsetAsync(d_ws, 0, 25 * sizeof(double), stream);

    dim3 grid(BB * NBD * NBH);   // 1024 blocks = 4/CU = 16 waves/CU at VGPR<=128
    rfcm_main<<<grid, NT, 0, stream>>>(yp, img, ws);
    rfcm_fin<<<1, 64, 0, stream>>>(ws, out);
}

// Round 4
// 126.585 us; speedup vs baseline: 1.0607x; 1.0468x over previous
//
#include <hip/hip_runtime.h>

// RFCM loss, fused single pass + finalize. B=2, K=4, D=H=W=128. Scalar out.
//
// mean(J1) = (1/(B*N)) * sum_{b,k} [ A_bk - Sim_bk^2 / Sm_bk ]
//   Sm=sum mem, Sim=sum mem*img, A=sum mem*img^2, mem=y_pred^2
// mean(J2) = (1/(B*N)) * sum_n [ Sm*Sbk - Sm^2 - sum_k m*bk + sum_k m^2 ]
//   bk = box27(mem_k) incl center, zero pad. s9 = 3x3 in-plane box sum.
//   Per plane t: diag band (M_t*S_t - M_t^2 + q - ctt), prev band
//   (M_t*S_{t-1} - ctp), next band emitted one step late (M_{t-1}*S_t - cpt,
//   gated i>0; epilog adds it for plane d0+SD). Zero history at d0=0.
//
// R14: wide loads + deep register ring. R13 post-mortem: VGPR=128 gate
// achieved (occ 8.4->16.1, VALU 18->26%) but dur 49.7->47.4 -- residency
// lever measured weak twice. Meanwhile fillBuffer does 6.5 TB/s at 8.7%
// occupancy, and the session's fastest kernel (R10 42.6) used 16B DMA vs
// R11/R13's 8B register loads. No pipe is near saturation (requests 5.8
// TB/s vs L2 34 TB/s; VALU 26%). => bottleneck is bytes-in-flight per
// wave, not wave count. This round:
//  - float4 loads (16B/lane): half-wave = one full 128-col row, so one
//    1KB wave-load covers 2 rows of a cluster plane; halo rows (rbase-1,
//    rbase+2) pack into a second load. 9 loads/step vs R13's 13, covering
//    2 rows vs 1 (4.5 vs 13 loads/row).
//  - vertical 3-sum: own^2 + partner-half m (shfl_xor 32) + halo^2*hsc.
//  - 3-deep plane ring (96 staging regs): prefetch distance 3 steps,
//    ~24KB in flight/wave, compiler emits counted vmcnt (never drains).
//  - SD=8, 512 blocks = 2 blocks/CU; VGPR target ~220 (hard gate <=256).
// NEVER __launch_bounds__ min-waves (R4/R6: VGPR=64 -> 240-330MB spills).

#define BB 2
#define KK 4
#define DD 128
#define HH 128
#define WW 128
#define PLANE (HH * WW)
#define CL (DD * PLANE)      // cluster stride (floats)
#define SD 8
#define NBD (DD / SD)        // 16
#define HR 8                 // rows/block = 4 waves x 2 rows
#define NBH (HH / HR)        // 16
#define NT 256

__global__ __launch_bounds__(NT) void rfcm_main(
    const float* __restrict__ yp, const float* __restrict__ img,
    double* __restrict__ ws)
{
    __shared__ double red[4 * 13];   // 416 B reduction scratch

    const int tid  = threadIdx.x;
    const int wv   = tid >> 6;       // wave 0..3
    const int L    = tid & 63;
    const int half = L >> 5;         // 0: row rbase, 1: row rbase+1
    const int wl   = L & 31;
    const int c0   = wl << 2;        // 4 cols per lane

    // XCD swizzle: slab (b,dsb) -> XCD slab%8; its 16 h-tiles share one L2.
    const int bid  = blockIdx.x;
    const int xcd  = bid & 7;
    const int idx  = bid >> 3;       // 0..63
    const int sl   = idx >> 4;       // 0..3
    const int ht   = idx & 15;
    const int slab = sl * 8 + xcd;   // 0..31
    const int b    = slab >> 4;
    const int dsb  = slab & 15;

    const int rbase = ht * HR + (wv << 1);
    const int r     = rbase + half;            // own row
    const int d0    = dsb * SD;

    // halo row for this half (clamped + zero-scaled at volume edge)
    const int   gr  = half ? rbase + 2 : rbase - 1;
    const int   gH  = gr < 0 ? 0 : (gr > HH - 1 ? HH - 1 : gr);
    const float hsc = (gr >= 0 && gr <= HH - 1) ? 1.f : 0.f;

    const bool okL = (wl > 0), okR = (wl < 31);

    const float* pO = yp  + (size_t)(b * KK) * CL + (size_t)r  * WW + c0;
    const float* pH = yp  + (size_t)(b * KK) * CL + (size_t)gH * WW + c0;
    const float* pI = img + (size_t)b * CL        + (size_t)r  * WW + c0;

    // 3-deep plane ring: 4 clusters x (own4 + halo4) per slot
    float4 o0[KK], a0[KK], o1[KK], a1[KK], o2[KK], a2[KK];

    auto lplane = [&](int t, float4* o, float4* a) {
        const size_t tp = (size_t)t * PLANE;
        #pragma unroll
        for (int k = 0; k < KK; k++) {
            o[k] = *(const float4*)(pO + (size_t)k * CL + tp);
            a[k] = *(const float4*)(pH + (size_t)k * CL + tp);
        }
    };

    // (own,halo) raw -> center squares m + 3x3 box sum s9
    auto extract = [&](const float4 o4, const float4 a4, float4& m, float4& s9) {
        m.x = o4.x * o4.x; m.y = o4.y * o4.y;
        m.z = o4.z * o4.z; m.w = o4.w * o4.w;
        float4 v;
        v.x = m.x + __shfl_xor(m.x, 32, 64);   // partner half-wave row
        v.y = m.y + __shfl_xor(m.y, 32, 64);
        v.z = m.z + __shfl_xor(m.z, 32, 64);
        v.w = m.w + __shfl_xor(m.w, 32, 64);
        v.x = fmaf(a4.x * a4.x, hsc, v.x);     // halo row
        v.y = fmaf(a4.y * a4.y, hsc, v.y);
        v.z = fmaf(a4.z * a4.z, hsc, v.z);
        v.w = fmaf(a4.w * a4.w, hsc, v.w);
        const float vl = okL ? __shfl_up(v.w, 1, 64)   : 0.f;
        const float vr = okR ? __shfl_down(v.x, 1, 64) : 0.f;
        const float t1 = v.x + v.y, t2 = v.z + v.w;
        s9.x = vl + t1; s9.y = t1 + v.z; s9.z = v.y + t2; s9.w = t2 + vr;
    };

    // ---- prolog: 3 plane batches + img in flight before first wait ----
    lplane((d0 > 0) ? d0 - 1 : 0, o0, a0);
    lplane(d0,     o1, a1);
    lplane(d0 + 1, o2, a2);
    float4 iv = *(const float4*)(pI + (size_t)d0 * PLANE);

    float4 mp[KK], sp[KK];
    float4 Mp = make_float4(0.f,0.f,0.f,0.f), Sp = make_float4(0.f,0.f,0.f,0.f);
    #pragma unroll
    for (int k = 0; k < KK; k++) {
        extract(o0[k], a0[k], mp[k], sp[k]);
        Mp.x += mp[k].x; Mp.y += mp[k].y; Mp.z += mp[k].z; Mp.w += mp[k].w;
        Sp.x += sp[k].x; Sp.y += sp[k].y; Sp.z += sp[k].z; Sp.w += sp[k].w;
    }
    if (d0 == 0) {   // no plane -1: zero history
        #pragma unroll
        for (int k = 0; k < KK; k++) {
            mp[k] = make_float4(0.f,0.f,0.f,0.f);
            sp[k] = make_float4(0.f,0.f,0.f,0.f);
        }
        Mp = make_float4(0.f,0.f,0.f,0.f); Sp = make_float4(0.f,0.f,0.f,0.f);
    }
    lplane(d0 + 2, o0, a0);          // d0+2 <= 122: always valid

    float smf[KK] = {0,0,0,0}, sif[KK] = {0,0,0,0}, saf[KK] = {0,0,0,0};
    float j2f = 0.f;

    // step i: consume plane t=d0+i from slot (i+1)%3; reload slot with t+3.
    auto step = [&](int i, float4* oS, float4* aS) {
        const int t = d0 + i;
        float4 ivn = iv;
        if (i < SD - 1) ivn = *(const float4*)(pI + (size_t)(t + 1) * PLANE);
        const bool rel = (i <= SD - 3) && (t + 3 < DD);
        const size_t tp3 = (size_t)(t + 3) * PLANE;

        const float4 iv2 = make_float4(iv.x*iv.x, iv.y*iv.y, iv.z*iv.z, iv.w*iv.w);
        float4 M = make_float4(0.f,0.f,0.f,0.f), S = make_float4(0.f,0.f,0.f,0.f);
        float q = 0.f, ctt = 0.f, ctp = 0.f, cpt = 0.f;

        #pragma unroll
        for (int k = 0; k < KK; k++) {
            float4 m, s9;
            extract(oS[k], aS[k], m, s9);
            if (rel) {                       // reload freed slot with t+3
                oS[k] = *(const float4*)(pO + (size_t)k * CL + tp3);
                aS[k] = *(const float4*)(pH + (size_t)k * CL + tp3);
            }
            M.x += m.x;  M.y += m.y;  M.z += m.z;  M.w += m.w;
            S.x += s9.x; S.y += s9.y; S.z += s9.z; S.w += s9.w;
            q   = fmaf(m.x,m.x,     fmaf(m.y,m.y,     fmaf(m.z,m.z,     fmaf(m.w,m.w,     q))));
            ctt = fmaf(m.x,s9.x,    fmaf(m.y,s9.y,    fmaf(m.z,s9.z,    fmaf(m.w,s9.w,    ctt))));
            ctp = fmaf(m.x,sp[k].x, fmaf(m.y,sp[k].y, fmaf(m.z,sp[k].z, fmaf(m.w,sp[k].w, ctp))));
            if (i > 0)
                cpt = fmaf(mp[k].x,s9.x, fmaf(mp[k].y,s9.y, fmaf(mp[k].z,s9.z, fmaf(mp[k].w,s9.w, cpt))));
            smf[k] += (m.x + m.y) + (m.z + m.w);
            sif[k] = fmaf(m.x,iv.x,  fmaf(m.y,iv.y,  fmaf(m.z,iv.z,  fmaf(m.w,iv.w,  sif[k]))));
            saf[k] = fmaf(m.x,iv2.x, fmaf(m.y,iv2.y, fmaf(m.z,iv2.z, fmaf(m.w,iv2.w, saf[k]))));
            mp[k] = m; sp[k] = s9;
        }

        j2f += (M.x*S.x + M.y*S.y + M.z*S.z + M.w*S.w)
             - (M.x*M.x + M.y*M.y + M.z*M.z + M.w*M.w)
             + q - ctt
             + (M.x*Sp.x + M.y*Sp.y + M.z*Sp.z + M.w*Sp.w) - ctp;
        if (i > 0)
            j2f += (Mp.x*S.x + Mp.y*S.y + Mp.z*S.z + Mp.w*S.w) - cpt;

        Mp = M; Sp = S;
        iv = ivn;
    };

    step(0, o1, a1); step(1, o2, a2); step(2, o0, a0);
    step(3, o1, a1); step(4, o2, a2); step(5, o0, a0);
    step(6, o1, a1); step(7, o2, a2);

    // epilog: next-band for plane d0+SD (slot 0; skipped at volume edge)
    if (d0 + SD < DD) {
        float4 S = make_float4(0.f,0.f,0.f,0.f);
        float cpt = 0.f;
        #pragma unroll
        for (int k = 0; k < KK; k++) {
            float4 m, s9;
            extract(o0[k], a0[k], m, s9);
            S.x += s9.x; S.y += s9.y; S.z += s9.z; S.w += s9.w;
            cpt = fmaf(mp[k].x,s9.x, fmaf(mp[k].y,s9.y, fmaf(mp[k].z,s9.z, fmaf(mp[k].w,s9.w, cpt))));
        }
        j2f += (Mp.x*S.x + Mp.y*S.y + Mp.z*S.z + Mp.w*S.w) - cpt;
    }

    // ---- block reduction of 13 scalars ----
    double qd[13];
    #pragma unroll
    for (int k = 0; k < KK; k++) {
        qd[k] = (double)smf[k]; qd[4 + k] = (double)sif[k]; qd[8 + k] = (double)saf[k];
    }
    qd[12] = (double)j2f;

    #pragma unroll
    for (int qq = 0; qq < 13; qq++) {
        double v = qd[qq];
        #pragma unroll
        for (int off = 32; off > 0; off >>= 1) v += __shfl_down(v, off, 64);
        qd[qq] = v;
    }

    const int lane = tid & 63, wid = tid >> 6;
    if (lane == 0) {
        #pragma unroll
        for (int qq = 0; qq < 13; qq++) red[wid * 13 + qq] = qd[qq];
    }
    __syncthreads();
    if (tid < 13) {
        const double sfin = red[tid] + red[13 + tid] + red[26 + tid] + red[39 + tid];
        int idxo;
        if      (tid < 4)  idxo = b * KK + tid;              // Sm
        else if (tid < 8)  idxo = 8  + b * KK + (tid - 4);   // Sim
        else if (tid < 12) idxo = 16 + b * KK + (tid - 8);   // A
        else               idxo = 24;                        // J2
        unsafeAtomicAdd(&ws[idxo], sfin);
    }
}

__global__ void rfcm_fin(const double* __restrict__ ws, float* __restrict__ out)
{
    if (threadIdx.x == 0 && blockIdx.x == 0) {
        double j1 = 0;
        #pragma unroll
        for (int i = 0; i < BB * KK; i++)
            j1 += ws[16 + i] - ws[8 + i] * ws[8 + i] / ws[i];
        const double invBN = 1.0 / ((double)BB * (double)DD * (double)HH * (double)WW);
        out[0] = (float)(j1 * invBN + 0.0008 * ws[24] * invBN);
    }
}

extern "C" void kernel_launch(void* const* d_in, const int* in_sizes, int n_in,
                              void* d_out, int out_size, void* d_ws, size_t ws_size,
                              hipStream_t stream) {
    const float* yp  = (const float*)d_in[0];   // y_pred [2,4,128,128,128]
    const float* img = (const float*)d_in[1];   // image  [2,1,128,128,128]
    float* out = (float*)d_out;
    double* ws = (double*)d_ws;

    hipMemsetAsync(d_ws, 0, 25 * sizeof(double), stream);

    dim3 grid(BB * NBD * NBH);   // 512 blocks, 2/CU
    rfcm_main<<<grid, NT, 0, stream>>>(yp, img, ws);
    rfcm_fin<<<1, 64, 0, stream>>>(ws, out);
}